// Round 1
// baseline (379.910 us; speedup 1.0000x reference)
//
#include <hip/hip_runtime.h>

// GCN structure exploited:
//  - x is [N,1] => layer-1 message aggregation is SCALAR (1 atomic/edge, not 16)
//  - output reads only node N-1 => layer-2 aggregation only needs edges with
//    dst == N-1 (~32 of 3.2M), recorded during the degree pass.

#define TAIL_CAP 4096

__global__ void k_deg_tail(const int* __restrict__ src, const int* __restrict__ dst,
                           int E, int n, int* __restrict__ deg,
                           int* __restrict__ tail_cnt, int* __restrict__ tail_src) {
    int e = blockIdx.x * blockDim.x + threadIdx.x;
    if (e >= E) return;
    int d = dst[e];
    atomicAdd(&deg[d], 1);
    if (d == n - 1) {
        int p = atomicAdd(tail_cnt, 1);
        if (p < TAIL_CAP) tail_src[p] = src[e];
    }
}

// dinv = 1/sqrt(deg+1)  (+1 = self loop); xd = x*dinv; s1 init with self-loop term.
__global__ void k_dinv(const float* __restrict__ x, const int* __restrict__ deg, int n,
                       float* __restrict__ dinv, float* __restrict__ xd,
                       float* __restrict__ s1) {
    int i = blockIdx.x * blockDim.x + threadIdx.x;
    if (i >= n) return;
    float dv = 1.0f / sqrtf((float)(deg[i] + 1));
    dinv[i] = dv;
    float v = x[i] * dv;
    xd[i] = v;
    s1[i] = v;   // self-loop contribution (pre dinv[d] factor)
}

// s1[d] += x[s]*dinv[s] for every edge. xd/s1 are 400KB each -> L2 resident.
__global__ void k_agg1(const int* __restrict__ src, const int* __restrict__ dst,
                       int E, const float* __restrict__ xd, float* __restrict__ s1) {
    int e = blockIdx.x * blockDim.x + threadIdx.x;
    if (e >= E) return;
    atomicAdd(&s1[dst[e]], xd[src[e]]);
}

// Per node: t = dinv*s1; h1 = relu(t*W1+b1) [16]; g[i][j] = dinv[i]*sum_c h1[c]*W2[c][j]
// (pre-multiplied by dinv[i] so the final kernel only sums g rows).
__global__ void k_h2(const float* __restrict__ s1, const float* __restrict__ dinv,
                     const float* __restrict__ W1, const float* __restrict__ b1,
                     const float* __restrict__ W2, int n, float* __restrict__ g) {
    __shared__ float sW1[16], sb1[16], sW2[128];
    int tid = threadIdx.x;
    if (tid < 16) { sW1[tid] = W1[tid]; sb1[tid] = b1[tid]; }
    if (tid < 128) sW2[tid] = W2[tid];
    __syncthreads();
    int i = blockIdx.x * blockDim.x + tid;
    if (i >= n) return;
    float dv = dinv[i];
    float t = dv * s1[i];
    float acc0 = 0.f, acc1 = 0.f, acc2 = 0.f, acc3 = 0.f;
    float acc4 = 0.f, acc5 = 0.f, acc6 = 0.f, acc7 = 0.f;
#pragma unroll
    for (int c = 0; c < 16; ++c) {
        float h1 = fmaxf(fmaf(t, sW1[c], sb1[c]), 0.f);
        const float* w = &sW2[c * 8];
        acc0 = fmaf(h1, w[0], acc0); acc1 = fmaf(h1, w[1], acc1);
        acc2 = fmaf(h1, w[2], acc2); acc3 = fmaf(h1, w[3], acc3);
        acc4 = fmaf(h1, w[4], acc4); acc5 = fmaf(h1, w[5], acc5);
        acc6 = fmaf(h1, w[6], acc6); acc7 = fmaf(h1, w[7], acc7);
    }
    float* o = &g[(size_t)i * 8];
    o[0] = dv * acc0; o[1] = dv * acc1; o[2] = dv * acc2; o[3] = dv * acc3;
    o[4] = dv * acc4; o[5] = dv * acc5; o[6] = dv * acc6; o[7] = dv * acc7;
}

// Single block: sum g rows for tail in-edges + self loop; relu(dinv*agg+b2)@Wfc+bfc.
__global__ void k_final(const float* __restrict__ g, const float* __restrict__ dinv,
                        const int* __restrict__ tail_cnt, const int* __restrict__ tail_src,
                        const float* __restrict__ b2, const float* __restrict__ Wfc,
                        const float* __restrict__ bfc, int n, float* __restrict__ out) {
    __shared__ float agg[8];
    int tid = threadIdx.x;
    if (tid < 8) agg[tid] = 0.f;
    __syncthreads();
    int cnt = *tail_cnt;
    if (cnt > TAIL_CAP) cnt = TAIL_CAP;
    int total = (cnt + 1) * 8;              // entry `cnt` is the self loop
    for (int idx = tid; idx < total; idx += blockDim.x) {
        int p = idx >> 3, j = idx & 7;
        int s = (p < cnt) ? tail_src[p] : (n - 1);
        atomicAdd(&agg[j], g[(size_t)s * 8 + j]);
    }
    __syncthreads();
    if (tid == 0) {
        float dv = dinv[n - 1];
        float o = 0.f;
#pragma unroll
        for (int j = 0; j < 8; ++j)
            o += fmaxf(fmaf(dv, agg[j], b2[j]), 0.f) * Wfc[j];
        out[0] = o + bfc[0];
    }
}

extern "C" void kernel_launch(void* const* d_in, const int* in_sizes, int n_in,
                              void* d_out, int out_size, void* d_ws, size_t ws_size,
                              hipStream_t stream) {
    const float* x   = (const float*)d_in[0];
    const int*   ei  = (const int*)d_in[1];
    const float* W1  = (const float*)d_in[2];
    const float* b1  = (const float*)d_in[3];
    const float* W2  = (const float*)d_in[4];
    const float* b2  = (const float*)d_in[5];
    const float* Wfc = (const float*)d_in[6];
    const float* bfc = (const float*)d_in[7];
    float* out = (float*)d_out;

    int n = in_sizes[0];
    int E = in_sizes[1] / 2;
    const int* src = ei;
    const int* dst = ei + E;

    // workspace layout (16B aligned)
    char* ws = (char*)d_ws;
    size_t off = 0;
    int* deg = (int*)(ws + off);       off += (size_t)n * 4;           // n*4 (=400000, 16B-aligned)
    int* tail_cnt = (int*)(ws + off);  off += 16;
    int* tail_src = (int*)(ws + off);  off += TAIL_CAP * 4;
    float* dinv = (float*)(ws + off);  off += (size_t)n * 4;
    float* xd   = (float*)(ws + off);  off += (size_t)n * 4;
    float* s1   = (float*)(ws + off);  off += (size_t)n * 4;
    float* g    = (float*)(ws + off);  off += (size_t)n * 8 * 4;

    // zero deg + tail_cnt (contiguous prefix)
    hipMemsetAsync(d_ws, 0, (size_t)n * 4 + 16, stream);

    int bE = (E + 255) / 256;
    int bN = (n + 255) / 256;
    k_deg_tail<<<bE, 256, 0, stream>>>(src, dst, E, n, deg, tail_cnt, tail_src);
    k_dinv<<<bN, 256, 0, stream>>>(x, deg, n, dinv, xd, s1);
    k_agg1<<<bE, 256, 0, stream>>>(src, dst, E, xd, s1);
    k_h2<<<bN, 256, 0, stream>>>(s1, dinv, W1, b1, W2, n, g);
    k_final<<<1, 256, 0, stream>>>(g, dinv, tail_cnt, tail_src, b2, Wfc, bfc, n, out);
}

// Round 2
// 185.367 us; speedup vs baseline: 2.0495x; 2.0495x over previous
//
#include <hip/hip_runtime.h>

// GCN structure exploited:
//  - x is [N,1] => layer-1 aggregation is SCALAR per node
//  - output reads only node N-1 => layer-2 aggregation only needs edges with
//    dst == N-1, found by scanning the last bucket of the dst-sorted edges.
// Global atomics eliminated (memory-side write-through at 32B/atomic was the
// Round-1 bottleneck: WRITE_SIZE = 3.2M x 32B = 100 MB per atomic pass).
// Instead: two-level counting sort by dst bucket (512 nodes/bucket), then
// per-bucket LDS histograms / fp32 bins with coalesced non-atomic flushes.

#define EPB 8192          // edges per block in hist/scatter
#define BSHIFT 9          // 512 nodes per bucket
#define BNODES 512
#define MAXBUCKET 256     // supports n up to 131072
#define SRCBITS 17        // src ids < 2^17 (n = 100000)
#define SRCMASK ((1u << SRCBITS) - 1u)

// --- pass A: per-block coarse histogram (LDS atomics only) ---
__global__ void k_hist(const int* __restrict__ dst, int E, int nbucket,
                       int* __restrict__ hist) {
    __shared__ int lh[MAXBUCKET];
    int tid = threadIdx.x;
    for (int j = tid; j < nbucket; j += 256) lh[j] = 0;
    __syncthreads();
    int base = blockIdx.x * EPB;
    for (int k = 0; k < EPB; k += 256) {
        int e = base + k + tid;
        if (e < E) atomicAdd(&lh[dst[e] >> BSHIFT], 1);
    }
    __syncthreads();
    int* out = hist + (size_t)blockIdx.x * nbucket;
    for (int j = tid; j < nbucket; j += 256) out[j] = lh[j];
}

// --- pass B: per-bucket column scan over block histograms (in-place) ---
__global__ void k_colscan(int* __restrict__ hist, int nblk, int nbucket,
                          int* __restrict__ totals) {
    int b = blockIdx.x;
    int lane = threadIdx.x;            // 64 threads = 1 wave
    int running = 0;
    for (int i0 = 0; i0 < nblk; i0 += 64) {
        int i = i0 + lane;
        int v = (i < nblk) ? hist[(size_t)i * nbucket + b] : 0;
        int incl = v;
        for (int off = 1; off < 64; off <<= 1) {
            int t = __shfl_up(incl, off, 64);
            if (lane >= off) incl += t;
        }
        if (i < nblk) hist[(size_t)i * nbucket + b] = running + (incl - v);
        running += __shfl(incl, 63, 64);
    }
    if (lane == 0) totals[b] = running;
}

// --- pass B2: exclusive scan of bucket totals -> bucket base offsets ---
__global__ void k_bucketbase(const int* __restrict__ totals, int nbucket, int E,
                             int* __restrict__ base) {
    __shared__ int t[MAXBUCKET];
    int tid = threadIdx.x;             // 256 threads
    int own = (tid < nbucket) ? totals[tid] : 0;
    t[tid] = own;
    __syncthreads();
    for (int off = 1; off < MAXBUCKET; off <<= 1) {
        int v = (tid >= off) ? t[tid - off] : 0;
        __syncthreads();
        t[tid] += v;
        __syncthreads();
    }
    if (tid < nbucket) base[tid] = t[tid] - own;   // exclusive
    if (tid == 0) base[nbucket] = E;
}

// --- pass C: scatter packed (dstLow | src) into dst-bucket-sorted order ---
__global__ void k_scatter(const int* __restrict__ src, const int* __restrict__ dst,
                          int E, int nbucket,
                          const int* __restrict__ hist, const int* __restrict__ base,
                          unsigned* __restrict__ sorted) {
    __shared__ int cur[MAXBUCKET];
    int tid = threadIdx.x;
    const int* h = hist + (size_t)blockIdx.x * nbucket;
    for (int j = tid; j < nbucket; j += 256) cur[j] = base[j] + h[j];
    __syncthreads();
    int bb = blockIdx.x * EPB;
    for (int k = 0; k < EPB; k += 256) {
        int e = bb + k + tid;
        if (e < E) {
            int d = dst[e], s = src[e];
            int b = d >> BSHIFT;
            int pos = atomicAdd(&cur[b], 1);
            sorted[pos] = ((unsigned)(d & (BNODES - 1)) << SRCBITS) | (unsigned)s;
        }
    }
}

// --- pass D: per-bucket degree histogram, coalesced non-atomic flush ---
__global__ void k_deg(const unsigned* __restrict__ sorted, const int* __restrict__ base,
                      int n, int* __restrict__ deg) {
    __shared__ int cnt[BNODES];
    int tid = threadIdx.x;
    int b = blockIdx.x;
    for (int j = tid; j < BNODES; j += 256) cnt[j] = 0;
    __syncthreads();
    int p0 = base[b], p1 = base[b + 1];
    for (int pos = p0 + tid; pos < p1; pos += 256)
        atomicAdd(&cnt[sorted[pos] >> SRCBITS], 1);
    __syncthreads();
    int nb = b << BSHIFT;
    for (int j = tid; j < BNODES; j += 256) {
        int node = nb + j;
        if (node < n) deg[node] = cnt[j];
    }
}

// dinv = 1/sqrt(deg+1) (+1 = self loop); xd = x*dinv
__global__ void k_dinv(const float* __restrict__ x, const int* __restrict__ deg, int n,
                       float* __restrict__ dinv, float* __restrict__ xd) {
    int i = blockIdx.x * blockDim.x + threadIdx.x;
    if (i >= n) return;
    float dv = rsqrtf((float)(deg[i] + 1));
    dinv[i] = dv;
    xd[i] = x[i] * dv;
}

// --- pass E: per-bucket fp32 LDS bins, coalesced flush (incl. self loop) ---
__global__ void k_s1(const unsigned* __restrict__ sorted, const int* __restrict__ base,
                     const float* __restrict__ xd, int n, float* __restrict__ s1) {
    __shared__ float bins[BNODES];
    int tid = threadIdx.x;
    int b = blockIdx.x;
    for (int j = tid; j < BNODES; j += 256) bins[j] = 0.f;
    __syncthreads();
    int p0 = base[b], p1 = base[b + 1];
    for (int pos = p0 + tid; pos < p1; pos += 256) {
        unsigned v = sorted[pos];
        atomicAdd(&bins[v >> SRCBITS], xd[v & SRCMASK]);
    }
    __syncthreads();
    int nb = b << BSHIFT;
    for (int j = tid; j < BNODES; j += 256) {
        int node = nb + j;
        if (node < n) s1[node] = bins[j] + xd[node];   // + self loop
    }
}

// Per node: t = dinv*s1; h1 = relu(t*W1+b1); g[i][:] = dinv[i]*(h1 @ W2)
__global__ void k_h2(const float* __restrict__ s1, const float* __restrict__ dinv,
                     const float* __restrict__ W1, const float* __restrict__ b1,
                     const float* __restrict__ W2, int n, float* __restrict__ g) {
    __shared__ float sW1[16], sb1[16], sW2[128];
    int tid = threadIdx.x;
    if (tid < 16) { sW1[tid] = W1[tid]; sb1[tid] = b1[tid]; }
    if (tid < 128) sW2[tid] = W2[tid];
    __syncthreads();
    int i = blockIdx.x * blockDim.x + tid;
    if (i >= n) return;
    float dv = dinv[i];
    float t = dv * s1[i];
    float acc0 = 0.f, acc1 = 0.f, acc2 = 0.f, acc3 = 0.f;
    float acc4 = 0.f, acc5 = 0.f, acc6 = 0.f, acc7 = 0.f;
#pragma unroll
    for (int c = 0; c < 16; ++c) {
        float h1 = fmaxf(fmaf(t, sW1[c], sb1[c]), 0.f);
        const float* w = &sW2[c * 8];
        acc0 = fmaf(h1, w[0], acc0); acc1 = fmaf(h1, w[1], acc1);
        acc2 = fmaf(h1, w[2], acc2); acc3 = fmaf(h1, w[3], acc3);
        acc4 = fmaf(h1, w[4], acc4); acc5 = fmaf(h1, w[5], acc5);
        acc6 = fmaf(h1, w[6], acc6); acc7 = fmaf(h1, w[7], acc7);
    }
    float* o = &g[(size_t)i * 8];
    o[0] = dv * acc0; o[1] = dv * acc1; o[2] = dv * acc2; o[3] = dv * acc3;
    o[4] = dv * acc4; o[5] = dv * acc5; o[6] = dv * acc6; o[7] = dv * acc7;
}

// Single block: scan the target node's bucket for dst==n-1, sum g rows + self.
__global__ void k_final(const unsigned* __restrict__ sorted, const int* __restrict__ base,
                        const float* __restrict__ g, const float* __restrict__ dinv,
                        const float* __restrict__ b2, const float* __restrict__ Wfc,
                        const float* __restrict__ bfc, int n, float* __restrict__ out) {
    __shared__ float agg[8];
    int tid = threadIdx.x;
    if (tid < 8) agg[tid] = 0.f;
    __syncthreads();
    int tgt = n - 1;
    int b = tgt >> BSHIFT;
    unsigned tLow = (unsigned)(tgt & (BNODES - 1));
    int p0 = base[b], p1 = base[b + 1];
    for (int pos = p0 + tid; pos < p1; pos += 256) {
        unsigned v = sorted[pos];
        if ((v >> SRCBITS) == tLow) {
            const float* gr = &g[(size_t)(v & SRCMASK) * 8];
#pragma unroll
            for (int j = 0; j < 8; ++j) atomicAdd(&agg[j], gr[j]);
        }
    }
    __syncthreads();
    if (tid == 0) {
        float dv = dinv[tgt];
        const float* gr = &g[(size_t)tgt * 8];   // self loop row
        float o = 0.f;
#pragma unroll
        for (int j = 0; j < 8; ++j)
            o += fmaxf(fmaf(dv, agg[j] + gr[j], b2[j]), 0.f) * Wfc[j];
        out[0] = o + bfc[0];
    }
}

extern "C" void kernel_launch(void* const* d_in, const int* in_sizes, int n_in,
                              void* d_out, int out_size, void* d_ws, size_t ws_size,
                              hipStream_t stream) {
    const float* x   = (const float*)d_in[0];
    const int*   ei  = (const int*)d_in[1];
    const float* W1  = (const float*)d_in[2];
    const float* b1  = (const float*)d_in[3];
    const float* W2  = (const float*)d_in[4];
    const float* b2  = (const float*)d_in[5];
    const float* Wfc = (const float*)d_in[6];
    const float* bfc = (const float*)d_in[7];
    float* out = (float*)d_out;

    int n = in_sizes[0];
    int E = in_sizes[1] / 2;
    const int* src = ei;
    const int* dst = ei + E;

    int nbucket = (n + BNODES - 1) >> BSHIFT;       // 196 for n=100000
    int nblk    = (E + EPB - 1) / EPB;              // 391 for E=3.2M

    auto align16 = [](size_t v) { return (v + 15) & ~(size_t)15; };
    char* ws = (char*)d_ws;
    size_t off = 0;
    int* hist       = (int*)(ws + off); off = align16(off + (size_t)nblk * nbucket * 4);
    int* totals     = (int*)(ws + off); off = align16(off + (size_t)nbucket * 4);
    int* bucketBase = (int*)(ws + off); off = align16(off + (size_t)(nbucket + 1) * 4);
    unsigned* sorted= (unsigned*)(ws + off); off = align16(off + (size_t)E * 4);
    int* deg        = (int*)(ws + off); off = align16(off + (size_t)n * 4);
    float* dinv     = (float*)(ws + off); off = align16(off + (size_t)n * 4);
    float* xd       = (float*)(ws + off); off = align16(off + (size_t)n * 4);
    float* s1       = (float*)(ws + off); off = align16(off + (size_t)n * 4);
    float* g        = (float*)(ws + off); off = align16(off + (size_t)n * 8 * 4);

    int bN = (n + 255) / 256;

    k_hist      <<<nblk,    256, 0, stream>>>(dst, E, nbucket, hist);
    k_colscan   <<<nbucket,  64, 0, stream>>>(hist, nblk, nbucket, totals);
    k_bucketbase<<<1,       256, 0, stream>>>(totals, nbucket, E, bucketBase);
    k_scatter   <<<nblk,    256, 0, stream>>>(src, dst, E, nbucket, hist, bucketBase, sorted);
    k_deg       <<<nbucket, 256, 0, stream>>>(sorted, bucketBase, n, deg);
    k_dinv      <<<bN,      256, 0, stream>>>(x, deg, n, dinv, xd);
    k_s1        <<<nbucket, 256, 0, stream>>>(sorted, bucketBase, xd, n, s1);
    k_h2        <<<bN,      256, 0, stream>>>(s1, dinv, W1, b1, W2, n, g);
    k_final     <<<1,       256, 0, stream>>>(sorted, bucketBase, g, dinv, b2, Wfc, bfc, n, out);
}

// Round 3
// 180.284 us; speedup vs baseline: 2.1073x; 1.0282x over previous
//
#include <hip/hip_runtime.h>

// Output reads ONLY node n-1  =>  work backwards through the dataflow:
//   out needs g[] for D = {n-1} U in-neighbors(n-1)        (~34 nodes)
//   g[d] needs s1[d] = sum xd[src] over edges into d        (~1100 edges)
//   xd[s] needs deg[s] for sources of those edges U D       (~1100 nodes)
// So we never compute full-graph deg/s1/h2. Three streaming scans of dst
// (12.8 MB each, membership via a 12.5KB L1-resident bitmap) + tiny finishers.
//   pass1: find edges dst==n-1            -> S1 multiset (sources)
//   bm1:   dedup S1 + {n-1}               -> Dlist, bitmap1
//   pass2: find edges dst in bitmap1      -> L2 edge list (src,dst)
//   bm2:   {L2 sources} U D               -> bitmap2
//   pass3: deg[d]++ for dst in bitmap2    (~37k atomics total)
//   final: single block computes s1/h1/g for D, aggregates at n-1, FC.

#define S1CAP 4096
#define DCAP  128
#define L2CAP 65536

__global__ void k_pass1(const int* __restrict__ src, const int* __restrict__ dst,
                        int E4, int E, int n, int* __restrict__ cnts,
                        int* __restrict__ S1) {
    int i = blockIdx.x * blockDim.x + threadIdx.x;
    int tgt = n - 1;
    if (i < E4) {
        int4 d4 = ((const int4*)dst)[i];
        int base = i * 4;
        if (d4.x == tgt) { int p = atomicAdd(&cnts[0], 1); if (p < S1CAP) S1[p] = src[base]; }
        if (d4.y == tgt) { int p = atomicAdd(&cnts[0], 1); if (p < S1CAP) S1[p] = src[base + 1]; }
        if (d4.z == tgt) { int p = atomicAdd(&cnts[0], 1); if (p < S1CAP) S1[p] = src[base + 2]; }
        if (d4.w == tgt) { int p = atomicAdd(&cnts[0], 1); if (p < S1CAP) S1[p] = src[base + 3]; }
    }
    if (i == 0) {
        for (int e = E4 * 4; e < E; ++e)
            if (dst[e] == tgt) { int p = atomicAdd(&cnts[0], 1); if (p < S1CAP) S1[p] = src[e]; }
    }
}

// dedup S1 + {n-1} into Dlist + bitmap1
__global__ void k_bm1(const int* __restrict__ S1, int n,
                      unsigned* __restrict__ bm1, int* __restrict__ cnts,
                      int* __restrict__ Dlist) {
    int cnt1 = cnts[0]; if (cnt1 > S1CAP) cnt1 = S1CAP;
    int total = cnt1 + 1;                      // extra entry = n-1 itself
    for (int p = threadIdx.x; p < total; p += blockDim.x) {
        int s = (p < cnt1) ? S1[p] : (n - 1);
        unsigned bit = 1u << (s & 31);
        unsigned old = atomicOr(&bm1[s >> 5], bit);
        if (!(old & bit)) {
            int q = atomicAdd(&cnts[1], 1);
            if (q < DCAP) Dlist[q] = s;
        }
    }
}

__global__ void k_pass2(const int* __restrict__ src, const int* __restrict__ dst,
                        int E4, int E, const unsigned* __restrict__ bm1,
                        int* __restrict__ cnts, int* __restrict__ L2src,
                        int* __restrict__ L2dst) {
    int i = blockIdx.x * blockDim.x + threadIdx.x;
    if (i < E4) {
        int4 d4 = ((const int4*)dst)[i];
        int base = i * 4;
        int dd[4] = {d4.x, d4.y, d4.z, d4.w};
#pragma unroll
        for (int k = 0; k < 4; ++k) {
            int d = dd[k];
            if ((bm1[d >> 5] >> (d & 31)) & 1u) {
                int p = atomicAdd(&cnts[2], 1);
                if (p < L2CAP) { L2src[p] = src[base + k]; L2dst[p] = d; }
            }
        }
    }
    if (i == 0) {
        for (int e = E4 * 4; e < E; ++e) {
            int d = dst[e];
            if ((bm1[d >> 5] >> (d & 31)) & 1u) {
                int p = atomicAdd(&cnts[2], 1);
                if (p < L2CAP) { L2src[p] = src[e]; L2dst[p] = d; }
            }
        }
    }
}

// bitmap2 = {L2 sources} U D
__global__ void k_bm2(const int* __restrict__ cnts, const int* __restrict__ L2src,
                      const int* __restrict__ Dlist, unsigned* __restrict__ bm2) {
    int cnt2 = cnts[2]; if (cnt2 > L2CAP) cnt2 = L2CAP;
    int cntD = cnts[1]; if (cntD > DCAP) cntD = DCAP;
    int total = cnt2 + cntD;
    for (int p = blockIdx.x * blockDim.x + threadIdx.x; p < total;
         p += gridDim.x * blockDim.x) {
        int s = (p < cnt2) ? L2src[p] : Dlist[p - cnt2];
        atomicOr(&bm2[s >> 5], 1u << (s & 31));
    }
}

__global__ void k_pass3(const int* __restrict__ dst, int E4, int E,
                        const unsigned* __restrict__ bm2, int* __restrict__ deg) {
    int i = blockIdx.x * blockDim.x + threadIdx.x;
    if (i < E4) {
        int4 d4 = ((const int4*)dst)[i];
        int dd[4] = {d4.x, d4.y, d4.z, d4.w};
#pragma unroll
        for (int k = 0; k < 4; ++k) {
            int d = dd[k];
            if ((bm2[d >> 5] >> (d & 31)) & 1u) atomicAdd(&deg[d], 1);
        }
    }
    if (i == 0) {
        for (int e = E4 * 4; e < E; ++e) {
            int d = dst[e];
            if ((bm2[d >> 5] >> (d & 31)) & 1u) atomicAdd(&deg[d], 1);
        }
    }
}

// single block: s1/h1/g for each d in D, then layer-2 agg at n-1, then FC.
__global__ void k_final(const float* __restrict__ x, const int* __restrict__ deg,
                        const int* __restrict__ cnts, const int* __restrict__ S1,
                        const int* __restrict__ Dlist, const int* __restrict__ L2src,
                        const int* __restrict__ L2dst, float* __restrict__ msgs,
                        const float* __restrict__ W1, const float* __restrict__ b1,
                        const float* __restrict__ W2, const float* __restrict__ b2,
                        const float* __restrict__ Wfc, const float* __restrict__ bfc,
                        int n, float* __restrict__ out) {
    __shared__ float gD[DCAP][8];
    __shared__ int sD[DCAP];
    __shared__ float sW1[16], sb1[16], sW2[128], agg[8];
    int tid = threadIdx.x;
    int cnt1 = cnts[0]; if (cnt1 > S1CAP) cnt1 = S1CAP;
    int cntD = cnts[1]; if (cntD > DCAP) cntD = DCAP;
    int cnt2 = cnts[2]; if (cnt2 > L2CAP) cnt2 = L2CAP;
    if (tid < 16) { sW1[tid] = W1[tid]; sb1[tid] = b1[tid]; }
    if (tid < 128) sW2[tid] = W2[tid];
    if (tid < 8) agg[tid] = 0.f;
    for (int i = tid; i < cntD; i += 256) sD[i] = Dlist[i];
    __syncthreads();
    // Phase A: per-edge messages m_e = x[s]*dinv[s]
    for (int e = tid; e < cnt2; e += 256) {
        int s = L2src[e];
        msgs[e] = x[s] * rsqrtf((float)(deg[s] + 1));
    }
    __syncthreads();
    // Phase B: one wave per d (wave-strided): s1 -> h1 -> g
    int wave = tid >> 6, lane = tid & 63;
    for (int di = wave; di < cntD; di += 4) {
        int d = sD[di];
        float acc = 0.f;
        for (int e = lane; e < cnt2; e += 64)
            if (L2dst[e] == d) acc += msgs[e];
        for (int off = 32; off; off >>= 1) acc += __shfl_down(acc, off, 64);
        if (lane == 0) {
            float dv = rsqrtf((float)(deg[d] + 1));
            float t = dv * (acc + x[d] * dv);          // + self-loop term
            float g8[8] = {0, 0, 0, 0, 0, 0, 0, 0};
#pragma unroll
            for (int c = 0; c < 16; ++c) {
                float h1 = fmaxf(fmaf(t, sW1[c], sb1[c]), 0.f);
#pragma unroll
                for (int j = 0; j < 8; ++j) g8[j] = fmaf(h1, sW2[c * 8 + j], g8[j]);
            }
#pragma unroll
            for (int j = 0; j < 8; ++j) gD[di][j] = dv * g8[j];
        }
    }
    __syncthreads();
    // Phase C: agg2[n-1] pre-factor = sum over S1 multiset of g[src] (+ self later)
    for (int p = tid; p < cnt1; p += 256) {
        int s = S1[p];
        int idx = 0;
        for (int i = 0; i < cntD; ++i) if (sD[i] == s) { idx = i; break; }
#pragma unroll
        for (int j = 0; j < 8; ++j) atomicAdd(&agg[j], gD[idx][j]);
    }
    __syncthreads();
    if (tid == 0) {
        int idxT = 0;
        for (int i = 0; i < cntD; ++i) if (sD[i] == n - 1) { idxT = i; break; }
        float dv = rsqrtf((float)(deg[n - 1] + 1));
        float o = 0.f;
#pragma unroll
        for (int j = 0; j < 8; ++j) {
            float a = dv * (agg[j] + gD[idxT][j]);     // + self-loop g[n-1]
            o += fmaxf(a + b2[j], 0.f) * Wfc[j];
        }
        out[0] = o + bfc[0];
    }
}

extern "C" void kernel_launch(void* const* d_in, const int* in_sizes, int n_in,
                              void* d_out, int out_size, void* d_ws, size_t ws_size,
                              hipStream_t stream) {
    const float* x   = (const float*)d_in[0];
    const int*   ei  = (const int*)d_in[1];
    const float* W1  = (const float*)d_in[2];
    const float* b1  = (const float*)d_in[3];
    const float* W2  = (const float*)d_in[4];
    const float* b2  = (const float*)d_in[5];
    const float* Wfc = (const float*)d_in[6];
    const float* bfc = (const float*)d_in[7];
    float* out = (float*)d_out;

    int n = in_sizes[0];
    int E = in_sizes[1] / 2;
    const int* src = ei;
    const int* dst = ei + E;

    size_t bmWords = ((size_t)(n + 31) / 32 + 1023) & ~(size_t)1023; // pad to 4KB
    char* ws = (char*)d_ws;
    size_t off = 0;
    int*      deg   = (int*)(ws + off);      off += (size_t)n * 4;        // n*4 (16B-aligned for n=100000)
    unsigned* bm1   = (unsigned*)(ws + off); off += bmWords * 4;
    unsigned* bm2   = (unsigned*)(ws + off); off += bmWords * 4;
    int*      cnts  = (int*)(ws + off);      off += 64;
    size_t zeroBytes = off;                  // deg + bm1 + bm2 + cnts
    int*      S1    = (int*)(ws + off);      off += S1CAP * 4;
    int*      Dlist = (int*)(ws + off);      off += ((DCAP * 4 + 15) & ~15);
    int*      L2src = (int*)(ws + off);      off += L2CAP * 4;
    int*      L2dst = (int*)(ws + off);      off += L2CAP * 4;
    float*    msgs  = (float*)(ws + off);    off += L2CAP * 4;

    hipMemsetAsync(d_ws, 0, zeroBytes, stream);

    int E4 = E / 4;
    int bE4 = (E4 + 255) / 256;

    k_pass1<<<bE4, 256, 0, stream>>>(src, dst, E4, E, n, cnts, S1);
    k_bm1  <<<1,   256, 0, stream>>>(S1, n, bm1, cnts, Dlist);
    k_pass2<<<bE4, 256, 0, stream>>>(src, dst, E4, E, bm1, cnts, L2src, L2dst);
    k_bm2  <<<8,   256, 0, stream>>>(cnts, L2src, Dlist, bm2);
    k_pass3<<<bE4, 256, 0, stream>>>(dst, E4, E, bm2, deg);
    k_final<<<1,   256, 0, stream>>>(x, deg, cnts, S1, Dlist, L2src, L2dst, msgs,
                                     W1, b1, W2, b2, Wfc, bfc, n, out);
}